// Round 12
// baseline (438.989 us; speedup 1.0000x reference)
//
#include <hip/hip_runtime.h>
#include <math.h>

#define NQ 256
#define NK 65536
#define DD 3072
#define TOPK 10
#define BN 64
#define BK 64
#define KTILES (DD / BK)              // 48
#define ATILE_BYTES (256 * BK * 2)    // 32768 B per k-tile bf16 image

typedef unsigned long long u64;
typedef unsigned int u32;
typedef unsigned short u16;

typedef __attribute__((ext_vector_type(8))) short short8;   // bf16x8 MFMA frag
typedef __attribute__((ext_vector_type(4))) float f32x4;
typedef __attribute__((ext_vector_type(4))) unsigned short us4;

#define GLDS(src, dst)                                                        \
  __builtin_amdgcn_global_load_lds(                                           \
      (const __attribute__((address_space(1))) void*)(src),                   \
      (__attribute__((address_space(3))) void*)(dst), 16, 0, 0)

__device__ __forceinline__ float fixv(float x) {
  if (isnan(x)) return 0.0f;
  if (isinf(x)) return x > 0.0f ? 1.0f : -1.0f;
  return x;
}

// RNE float -> bf16 bits
__device__ __forceinline__ u16 f2bf(float x) {
  u32 u = __float_as_uint(x);
  u32 r = (u + 0x7fffu + ((u >> 16) & 1u)) >> 16;
  return (u16)r;
}

// Order-preserving map: larger score -> larger key; ties -> smaller idx wins.
__device__ __forceinline__ u64 makekey(float f, int idx) {
  u32 u = __float_as_uint(f);
  u = (u & 0x80000000u) ? ~u : (u | 0x80000000u);
  return ((u64)u << 32) | (u32)(~(u32)idx);
}

// ---------- kernel 1: nan_to_num + normalize queries ----------
// Outputs: qn fp32 (rescore) + pre-swizzled bf16 A-tile image (GEMM staging)
__global__ __launch_bounds__(256) void qnorm_kernel(const float* __restrict__ query,
                                                    float* __restrict__ qn,
                                                    u16* __restrict__ apre) {
  const int m = blockIdx.x;
  const int t = threadIdx.x;
  const float4* qp = (const float4*)(query + (size_t)m * DD);
  float4 v[3];
  float s = 0.0f;
#pragma unroll
  for (int i = 0; i < 3; ++i) {
    float4 x = qp[t + i * 256];
    x.x = fixv(x.x); x.y = fixv(x.y); x.z = fixv(x.z); x.w = fixv(x.w);
    v[i] = x;
    s += x.x * x.x + x.y * x.y + x.z * x.z + x.w * x.w;
  }
#pragma unroll
  for (int off = 32; off > 0; off >>= 1) s += __shfl_xor(s, off);
  __shared__ float red[4];
  if ((t & 63) == 0) red[t >> 6] = s;
  __syncthreads();
  float inv = 1.0f / fmaxf(sqrtf(red[0] + red[1] + red[2] + red[3]), 1e-12f);
#pragma unroll
  for (int i = 0; i < 3; ++i) {
    float4 x = v[i];
    x.x *= inv; x.y *= inv; x.z *= inv; x.w *= inv;
    ((float4*)(qn + (size_t)m * DD))[t + i * 256] = x;
    // pre-swizzled bf16 image: tile kt, row m (128 B), byte ^= (m&7)<<4
    int k0 = (t + i * 256) * 4;
    int kt = k0 >> 6;
    int kk = k0 & 63;
    u32 off = (u32)kt * ATILE_BYTES + (((u32)(m * 128 + kk * 2)) ^ (((u32)m & 7) << 4));
    us4 b;
    b.x = f2bf(x.x); b.y = f2bf(x.y); b.z = f2bf(x.z); b.w = f2bf(x.w);
    *(us4*)((char*)apre + off) = b;
  }
}

// ---------- kernel 2: bf16 MFMA score GEMM + fused key-norm ----------
// r3 pipeline, re-geometried for occupancy WITHOUT spill: 512 threads,
// 8 waves x (32x64) wave tile -> acc[2][4] = 32 AGPR, est ~105 unified regs
// < 128 cap -> __launch_bounds__(512,4) = 2 blocks/CU = 16 waves/CU (vs 12).
// Same LDS layouts/swizzles, same 2-barrier loop, keys still read once.
__global__ __launch_bounds__(512, 4) void gemm_kernel(const u16* __restrict__ apre,
                                                      const float* __restrict__ keys,
                                                      float* __restrict__ invk,
                                                      float* __restrict__ scores) {
  __shared__ __align__(16) u16 As[256 * BK];  // 32 KB swizzled
  __shared__ __align__(16) u16 Bs[BN * BK];   // 8 KB swizzled
  __shared__ float sinv[BN];
  const int t = threadIdx.x;
  const int w = t >> 6, l = t & 63;
  const int n0 = blockIdx.x * BN;

  f32x4 acc[2][4];
#pragma unroll
  for (int mi = 0; mi < 2; ++mi)
#pragma unroll
    for (int ni = 0; ni < 4; ++ni) acc[mi][ni] = (f32x4){0.f, 0.f, 0.f, 0.f};
  float ssq = 0.0f;             // partial for row t>>3 (8 threads/row)

  const int brow = t >> 3;      // 0..63
  const int bco = (t & 7) * 8;  // fp32 col {0,8,...,56}

  for (int kt = 0; kt < KTILES; ++kt) {
    __syncthreads();  // previous tile's reads complete
    // A tile: 32 KB async DMA from pre-swizzled image (4 chunks/thread)
    const char* asrc = (const char*)apre + (size_t)kt * ATILE_BYTES;
#pragma unroll
    for (int i = 0; i < 4; ++i)
      GLDS(asrc + i * 8192 + t * 16, (char*)As + i * 8192 + t * 16);
    // B tile: 64x64 fp32 -> ssq + bf16 -> swizzled LDS (1 row/thread, 8 floats)
    const int kb = kt * BK;
    {
      const float* bp = keys + (size_t)(n0 + brow) * DD + kb + bco;
      float4 v0 = *(const float4*)(bp);
      float4 v1 = *(const float4*)(bp + 4);
      ssq += v0.x * v0.x + v0.y * v0.y + v0.z * v0.z + v0.w * v0.w +
             v1.x * v1.x + v1.y * v1.y + v1.z * v1.z + v1.w * v1.w;
      us4 b0, b1;
      b0.x = f2bf(v0.x); b0.y = f2bf(v0.y); b0.z = f2bf(v0.z); b0.w = f2bf(v0.w);
      b1.x = f2bf(v1.x); b1.y = f2bf(v1.y); b1.z = f2bf(v1.z); b1.w = f2bf(v1.w);
      u32 off = ((u32)(brow * 128 + bco * 2)) ^ (((u32)brow & 7) << 4);
      *(us4*)((char*)Bs + off) = b0;       // bytes [off, off+8)
      *(us4*)((char*)Bs + off + 8) = b1;   // same 16B chunk -> swizzle-consistent
    }
    __syncthreads();  // DMA + ds_writes visible
#pragma unroll
    for (int ks = 0; ks < 2; ++ks) {
      short8 a[2], b[4];
#pragma unroll
      for (int mi = 0; mi < 2; ++mi) {
        int row = w * 32 + mi * 16 + (l & 15);
        u32 off = ((u32)(row * 128 + ks * 64 + (l >> 4) * 16)) ^ (((u32)row & 7) << 4);
        a[mi] = *(const short8*)((const char*)As + off);
      }
#pragma unroll
      for (int ni = 0; ni < 4; ++ni) {
        int row = ni * 16 + (l & 15);
        u32 off = ((u32)(row * 128 + ks * 64 + (l >> 4) * 16)) ^ (((u32)row & 7) << 4);
        b[ni] = *(const short8*)((const char*)Bs + off);
      }
#pragma unroll
      for (int mi = 0; mi < 2; ++mi)
#pragma unroll
        for (int ni = 0; ni < 4; ++ni)
          acc[mi][ni] = __builtin_amdgcn_mfma_f32_16x16x32_bf16(a[mi], b[ni], acc[mi][ni], 0, 0, 0);
    }
  }

  // key inverse norms: 8 threads/row, consecutive lanes -> shfl groups of 8
  {
    float s = ssq;
    s += __shfl_xor(s, 1); s += __shfl_xor(s, 2); s += __shfl_xor(s, 4);
    if ((t & 7) == 0) {
      float iv = 1.0f / fmaxf(sqrtf(s), 1e-12f);
      sinv[brow] = iv;
      invk[n0 + brow] = iv;  // unique writer: this block owns these keys
    }
  }
  __syncthreads();

  // epilogue: scale + store. C frag: col=lane&15, row=(lane>>4)*4+r
#pragma unroll
  for (int ni = 0; ni < 4; ++ni) {
    int nl = ni * 16 + (l & 15);
    float iv = sinv[nl];
#pragma unroll
    for (int mi = 0; mi < 2; ++mi) {
      int q = w * 32 + mi * 16 + (l >> 4) * 4;
#pragma unroll
      for (int r = 0; r < 4; ++r)
        scores[(size_t)(q + r) * NK + n0 + nl] = acc[mi][ni][r] * iv;
    }
  }
}

// ---------- kernel 3: per-query full top-16 + exact rescore -> top-10 ----------
// One block per query (256 blocks). Streams the whole 64K row, per-thread
// top-16 over 256 strided elems, wave->block merge, exact fp32 rescore
// (identical math to validated r3), writes ord + out_idx.
__global__ __launch_bounds__(256) void topk_merge(const float* __restrict__ scores,
                                                  const float* __restrict__ qn,
                                                  const float* __restrict__ keys,
                                                  const float* __restrict__ invk,
                                                  int* __restrict__ ordws,
                                                  float* __restrict__ out_idx) {
  const int b = blockIdx.x;
  const int t = threadIdx.x;
  const int w = t >> 6, l = t & 63;
  const float4* row4 = (const float4*)(scores + (size_t)b * NK);
  __shared__ u64 wtop[64];
  __shared__ u64 top16[16];
  __shared__ float exact[16];

  // per-thread top-16 over its 256 strided elements (64 float4 loads)
  u64 c16[16];
#pragma unroll
  for (int i = 0; i < 4; ++i) {
    float4 v = row4[i * 256 + t];
    int nb = (i * 256 + t) * 4;
    c16[i * 4 + 0] = makekey(v.x, nb + 0);
    c16[i * 4 + 1] = makekey(v.y, nb + 1);
    c16[i * 4 + 2] = makekey(v.z, nb + 2);
    c16[i * 4 + 3] = makekey(v.w, nb + 3);
  }
  u64 mn = c16[0];
#pragma unroll
  for (int i = 1; i < 16; ++i) mn = c16[i] < mn ? c16[i] : mn;

#pragma unroll 4
  for (int i = 4; i < 64; ++i) {
    float4 v = row4[i * 256 + t];
    int nb = (i * 256 + t) * 4;
    float e[4] = {v.x, v.y, v.z, v.w};
#pragma unroll
    for (int j = 0; j < 4; ++j) {
      u64 kk = makekey(e[j], nb + j);
      if (kk > mn) {
#pragma unroll
        for (int q = 0; q < 16; ++q)
          if (c16[q] == mn) c16[q] = kk;  // unique match (keys distinct)
        u64 m2 = c16[0];
#pragma unroll
        for (int q = 1; q < 16; ++q) m2 = c16[q] < m2 ? c16[q] : m2;
        mn = m2;
      }
    }
  }

  // wave-level top-16 (16 rounds shfl-max, owner clears)
#pragma unroll 1
  for (int r = 0; r < 16; ++r) {
    u64 best = 0;
#pragma unroll
    for (int i = 0; i < 16; ++i) best = c16[i] > best ? c16[i] : best;
    u64 wb = best;
#pragma unroll
    for (int off = 1; off < 64; off <<= 1) {
      u64 o = __shfl_xor(wb, off);
      wb = o > wb ? o : wb;
    }
#pragma unroll
    for (int i = 0; i < 16; ++i)
      if (c16[i] == wb) c16[i] = 0;
    if (l == 0) wtop[w * 16 + r] = wb;
  }
  __syncthreads();
  if (w == 0) {  // wave 0: merge 4x16 -> global top-16
    u64 e = wtop[l];
#pragma unroll 1
    for (int r = 0; r < 16; ++r) {
      u64 wb = e;
#pragma unroll
      for (int off = 1; off < 64; off <<= 1) {
        u64 o = __shfl_xor(wb, off);
        wb = o > wb ? o : wb;
      }
      if (e == wb) e = 0;
      if (l == 0) top16[r] = wb;
    }
  }
  __syncthreads();

  // exact fp32 rescore: 16 threads per candidate (identical to r3 math)
  {
    const int g = t >> 4, c = t & 15;
    const int idx = (int)(~(u32)top16[g]);
    const float iv = invk[idx];
    const float4* kp = (const float4*)(keys + (size_t)idx * DD);
    const float4* qp = (const float4*)(qn + (size_t)b * DD);
    float s = 0.0f;
    for (int j = 0; j < 48; ++j) {
      float4 kv = kp[j * 16 + c];
      float4 qv = qp[j * 16 + c];
      s = fmaf(qv.x, kv.x * iv, s);
      s = fmaf(qv.y, kv.y * iv, s);
      s = fmaf(qv.z, kv.z * iv, s);
      s = fmaf(qv.w, kv.w * iv, s);
    }
    s += __shfl_xor(s, 1); s += __shfl_xor(s, 2);
    s += __shfl_xor(s, 4); s += __shfl_xor(s, 8);
    if (c == 0) exact[g] = s;
  }
  __syncthreads();

  if (w == 0 && l < 16) {  // top-10 of 16 by exact score
    u64 ek = makekey(exact[l], (int)(~(u32)top16[l]));
#pragma unroll 1
    for (int r = 0; r < TOPK; ++r) {
      u64 wb = ek;
#pragma unroll
      for (int off = 1; off < 16; off <<= 1) {
        u64 o = __shfl_xor(wb, off);
        wb = o > wb ? o : wb;
      }
      if (wb == ek) ek = 0;
      if (l == 0) {
        int idx = (int)(~(u32)wb);
        ordws[b * TOPK + r] = idx;
        out_idx[b * TOPK + r] = (float)idx;
      }
    }
  }
}

// ---------- kernel 4: parallel gather (one block per (query, rank)) ----------
__global__ __launch_bounds__(256) void gather_kernel(const int* __restrict__ ordws,
                                                     const float* __restrict__ keys,
                                                     float* __restrict__ out_emb) {
  const int t = threadIdx.x;
  const int idx = ordws[blockIdx.x];
  const float4* src = (const float4*)(keys + (size_t)idx * DD);
  float4* dst = (float4*)(out_emb + (size_t)blockIdx.x * DD);
#pragma unroll
  for (int c = 0; c < 3; ++c) dst[t + c * 256] = src[t + c * 256];
}

extern "C" void kernel_launch(void* const* d_in, const int* in_sizes, int n_in,
                              void* d_out, int out_size, void* d_ws, size_t ws_size,
                              hipStream_t stream) {
  const float* query = (const float*)d_in[0];
  const float* keys  = (const float*)d_in[1];

  float* ws = (float*)d_ws;
  float* invk   = ws;                                        // NK floats
  float* qn     = ws + NK;                                   // NQ*DD floats
  u16*   apre   = (u16*)(ws + NK + (size_t)NQ * DD);         // 48*256*64 bf16
  float* scores = ws + NK + (size_t)NQ * DD + (size_t)KTILES * 256 * BK / 2;  // NQ*NK
  int*   ordws  = (int*)(scores + (size_t)NQ * NK);          // NQ*TOPK ints

  float* out_emb = (float*)d_out;
  float* out_idx = (float*)d_out + (size_t)NQ * TOPK * DD;

  qnorm_kernel<<<NQ, 256, 0, stream>>>(query, qn, apre);
  gemm_kernel<<<NK / BN, 512, 0, stream>>>(apre, keys, invk, scores);
  topk_merge<<<NQ, 256, 0, stream>>>(scores, qn, keys, invk, ordws, out_idx);
  gather_kernel<<<NQ * TOPK, 256, 0, stream>>>(ordws, keys, out_emb);
}